// Round 5
// baseline (176.491 us; speedup 1.0000x reference)
//
#include <hip/hip_runtime.h>

// CatNet_76553497084407 — SLAYER-style spiking CNN, fully collapsed over time.
//
// R12: raise resident waves 16 -> 32 per CU. Five rounds of evidence:
// R7(41.8) = R8(conflicts/divide cut, 40.7) = R11(2 barrier domains, 41.4),
// R9(+15% LDS traffic) = +16% time. Model: VALU (~45%) and DS (~40%) pipes
// serialize WITHIN each wave; 16 waves/CU (occupancy 35%) can't overlap them
// across waves. Fix: quarter-image blocks, grid 1024 x 512 thr = 4 blocks/CU
// = 32 waves. LDS 4x34.8=139KB <= 160 OK. VGPR must stay <=64 -> bounds(512,8).
//   * Phases 2/4 pack lanes as (col, jj): thread owns 2 out-ch -> lane util
//     87%/66%, VALU issue per CU unchanged (+~20% halo recompute).
//   * Discriminator: if DS-instruction-throughput-bound (rival model), DS
//     wave-instrs double (same bytes) -> time gets WORSE -> next round cuts
//     DS instrs on R8 base instead.
//   * Keep: s_load weights (R9 lesson), even/odd r1p split, exact c/50 LDS
//     rate table, 2e-4 risky threshold, no-ballot pooled rate, float2 phase 0,
//     __device__ g_part partials + finish kernel (no d_ws).
// Spill tripwire: WRITE_SIZE must stay ~tens of KB.

#define T_STEPS 50
#define THETA   0.9999f

__device__ float g_part[256 * 16];   // [n][quarter][o] partial dense sums

// Exact-rounding rate: tbl[c] == c/50.0f computed with a true divide once.
__device__ __forceinline__ float spike_rate(float a, const float* __restrict__ tbl) {
    constexpr float INV = 50.0f / 0.9999f;
    float t = a * INV;
    float c = fminf(fmaxf(floorf(t), 0.0f), 50.0f);
    // fall back to the exact 50-step f32 sim when t is near an integer
    bool risky = (t > 0.5f) && (fabsf(t - rintf(t)) < 2e-4f);
    if (__ballot(risky)) {
        float v = 0.f, cnt = 0.f;
#pragma unroll 1
        for (int k = 0; k < T_STEPS; ++k) {
            v += a;
            float s = (v >= THETA) ? 1.0f : 0.0f;
            v -= s * THETA;
            cnt += s;
        }
        c = cnt;
    }
    return tbl[(int)c];
}

// No-ballot variant: only legal when the input provably cannot sit within
// 2e-4 of an integer boundary in t-units (pooled path: 1.1*k/50, margin 1.1e-3).
__device__ __forceinline__ float spike_rate_nb(float a, const float* __restrict__ tbl) {
    constexpr float INV = 50.0f / 0.9999f;
    float t = a * INV;
    float c = fminf(fmaxf(floorf(t), 0.0f), 50.0f);
    return tbl[(int)c];
}

extern "C" __global__ void __launch_bounds__(512, 8)
catnet_split(const float* __restrict__ x,
             const float* __restrict__ w1, const float* __restrict__ b1,
             const float* __restrict__ w2, const float* __restrict__ b2,
             const float* __restrict__ w3, const float* __restrict__ b3,
             const float* __restrict__ wf)
{
    const int n    = blockIdx.x >> 2;
    const int qt   = blockIdx.x & 3;
    const int tid  = threadIdx.x;
    const int wave = tid >> 6;
    const int lane = tid & 63;

    // Quarter ranges (derived from conv chain):
    //   h  (conv3 out)  : [h_lo, h_lo+h_cnt)
    //   p  (pool col)   : [h_lo-1, h_hi+6) clamped  -> [p_lo, p_lo+p_cnt)
    //   r1 (conv1 rows) : [2p_lo-1, 2p_hi+8) clamp  -> [r1_lo, r1_lo+r1_cnt)
    //   x  rows         : [r1_lo-1, r1_hi+1) clamp  -> [x_lo, x_lo+x_cnt)
    const int h_lo_t[4]  = {0, 21, 42, 63},  h_cnt_t[4]  = {21, 21, 21, 20};
    const int p_lo_t[4]  = {0, 20, 41, 62},  p_cnt_t[4]  = {27, 28, 28, 25};
    const int r1_lo_t[4] = {0, 39, 81, 123}, r1_cnt_t[4] = {62, 65, 65, 57};
    const int x_lo_t[4]  = {0, 38, 80, 122}, x_cnt_t[4]  = {63, 67, 67, 58};
    const int h_lo  = h_lo_t[qt],  h_cnt  = h_cnt_t[qt];
    const int p_lo  = p_lo_t[qt],  p_cnt  = p_cnt_t[qt];
    const int r1_lo = r1_lo_t[qt], r1_cnt = r1_cnt_t[qt];
    const int x_lo  = x_lo_t[qt],  x_cnt  = x_cnt_t[qt];

    __shared__ float xbar[182];                  // [h+1], global padded idx
    __shared__ float r1pe[16][92];               // even padded-h: H=2i -> [c][i]
    __shared__ float r1po[16][92];               // odd  padded-h: H=2i+1 -> [c][i]
    __shared__ float r3p[32][89];                // [c][p+1], global padded idx
    __shared__ alignas(16) float r4s[32][83];
    __shared__ float ratetbl[51];                // exact c/50.0f
    __shared__ float part[8];

    // zero conv pads + build exact-rate table (pads harmless if unused by qt)
    if (tid < 16)                { r1pe[tid][0] = 0.f; }            // H=0
    if (tid >= 16 && tid < 32)   { r1po[tid-16][90] = 0.f; }        // H=181
    if (tid >= 32 && tid < 64)   { r3p[tid-32][0] = 0.f; r3p[tid-32][88] = 0.f; }
    if (tid == 64)               { xbar[0] = 0.f; xbar[181] = 0.f; }
    if (tid >= 128 && tid < 179) { ratetbl[tid-128] = (float)(tid-128) / 50.0f; }

    // ---- phase 0: time-sum of this quarter's x rows, 4 lanes per row ----
    const float* xn = x + (size_t)n * (180 * 50);
    if (tid < 4 * x_cnt) {
        const int h_l = tid >> 2, q = tid & 3;
        const int h   = x_lo + h_l;
        const float2* row2 = reinterpret_cast<const float2*>(xn + h * 50);
        float s = 0.f;
        for (int k = q; k < 24; k += 4) { float2 v = row2[k]; s += v.x + v.y; }
        if (q == 0)                     { float2 v = row2[24]; s += v.x + v.y; }
        s += __shfl_xor(s, 1, 4);
        s += __shfl_xor(s, 2, 4);
        if (q == 0) xbar[h + 1] = s;
    }
    __syncthreads();

    // ---- phase 1: conv1 (1->16, k=3, pad=1), /T, +b1, rate; quarter rows ----
    for (int idx = tid; idx < 16 * 128; idx += 512) {
        const int c = idx >> 7, h_l = idx & 127;
        const bool act = h_l < r1_cnt;
        const int h = r1_lo + (act ? h_l : 0);
        float a = w1[c*3+0] * xbar[h] + w1[c*3+1] * xbar[h+1] + w1[c*3+2] * xbar[h+2];
        a = a / 50.0f + b1[c];
        float r = spike_rate(a, ratetbl);
        if (act) {
            int H = h + 1;
            if (H & 1) r1po[c][H >> 1] = r;
            else       r1pe[c][H >> 1] = r;
        }
    }
    __syncthreads();

    // ---- phase 2: conv2 (16->32, k=9, pad=1) + rate + pool(2)*1.1 + rate ----
    // 8 waves = 8 out-ch groups g of 4. Lane packing: (pool col, jj) pairs,
    // jj selects a 2-channel sub-pair -> 2*p_cnt (<=56) active lanes. Lane
    // pairs share the window address (LDS broadcast). Weights uniform s_load.
    {
        const int g   = __builtin_amdgcn_readfirstlane(wave);   // 0..7
        const int jj  = lane & 1;               // 2-ch sub-pair
        const int pl  = lane >> 1;              // 0..31
        const bool act = pl < p_cnt;
        const int p   = p_lo + (act ? pl : 0);
        const float* wb = w2 + (g * 4 + jj * 2) * 144;   // [j][ci][kh]

        float a0[2], a1[2];
#pragma unroll
        for (int j = 0; j < 2; ++j) { a0[j] = b2[g*4 + jj*2 + j]; a1[j] = a0[j]; }

        float we[5], wo[5];
#pragma unroll
        for (int d = 0; d < 5; ++d) { we[d] = r1pe[0][p + d]; wo[d] = r1po[0][p + d]; }

#pragma unroll 1
        for (int ci = 0; ci < 16; ++ci) {
            // prefetch next ci's window (clamped: last iter re-reads row 15)
            const int cn = (ci < 15) ? ci + 1 : 15;
            float weN[5], woN[5];
#pragma unroll
            for (int d = 0; d < 5; ++d) { weN[d] = r1pe[cn][p + d]; woN[d] = r1po[cn][p + d]; }

#pragma unroll
            for (int j = 0; j < 2; ++j) {
                const float* wj = wb + j * 144 + ci * 9;
#pragma unroll
                for (int kh = 0; kh < 9; ++kh) {
                    float wv  = wj[kh];
                    float xlo = (kh & 1) ? wo[kh >> 1] : we[kh >> 1];        // w[kh]
                    float xhi = (kh & 1) ? we[(kh + 1) >> 1] : wo[kh >> 1];  // w[kh+1]
                    a0[j] += wv * xlo;     // h = 2p
                    a1[j] += wv * xhi;     // h = 2p+1
                }
            }
#pragma unroll
            for (int d = 0; d < 5; ++d) { we[d] = weN[d]; wo[d] = woN[d]; }
        }
#pragma unroll
        for (int j = 0; j < 2; ++j) {
            float r20 = spike_rate(a0[j], ratetbl);
            float r21 = spike_rate(a1[j], ratetbl);
            float r3  = spike_rate_nb(1.1f * (r20 + r21), ratetbl);
            if (act) r3p[g*4 + jj*2 + j][p + 1] = r3;
        }
    }
    __syncthreads();

    // ---- phase 4: conv3 (32->32, k=7, pad=1) + rate; quarter h rows ----
    // 8 waves = 8 out-ch groups of 4; lane packing (h, jj), thread owns 2 ch.
    {
        const int gg   = __builtin_amdgcn_readfirstlane(wave);   // 0..7
        const int jj   = lane & 1;
        const int hl   = lane >> 1;             // 0..31
        const bool act = hl < h_cnt;
        const int h0   = h_lo + (act ? hl : 0);
        const float* wb = w3 + (gg * 4 + jj * 2) * 224;   // [j][ci][kh]

        float a[2];
#pragma unroll
        for (int j = 0; j < 2; ++j) a[j] = b3[gg*4 + jj*2 + j];

        float rv[7];
#pragma unroll
        for (int kh = 0; kh < 7; ++kh) rv[kh] = r3p[0][h0 + kh];

#pragma unroll 1
        for (int ci = 0; ci < 32; ++ci) {
            const int cn = (ci < 31) ? ci + 1 : 31;
            float rn[7];
#pragma unroll
            for (int kh = 0; kh < 7; ++kh) rn[kh] = r3p[cn][h0 + kh];

#pragma unroll
            for (int j = 0; j < 2; ++j) {
                const float* wj = wb + j * 224 + ci * 7;
#pragma unroll
                for (int kh = 0; kh < 7; ++kh)
                    a[j] += wj[kh] * rv[kh];
            }
#pragma unroll
            for (int kh = 0; kh < 7; ++kh) rv[kh] = rn[kh];
        }
#pragma unroll
        for (int j = 0; j < 2; ++j) {
            float r = spike_rate(a[j], ratetbl);
            if (act) r4s[gg*4 + jj*2 + j][h0] = r;
        }
    }
    __syncthreads();

    // ---- phase 5: partial dense over quarter h rows; 2 waves per output ----
    {
        const int o = wave >> 1, q = wave & 1;
        float acc = 0.f;
        if (lane < h_cnt) {
            const int h0 = h_lo + lane;
            const float* wo = wf + o * (32 * 83);
            for (int c = q; c < 32; c += 2)
                acc += r4s[c][h0] * wo[c * 83 + h0];
        }
#pragma unroll
        for (int off = 32; off > 0; off >>= 1)
            acc += __shfl_down(acc, off, 64);
        if (lane == 0) part[wave] = acc;
    }
    __syncthreads();
    if (tid < 4)
        g_part[n * 16 + qt * 4 + tid] = part[2 * tid] + part[2 * tid + 1];
}

extern "C" __global__ void __launch_bounds__(256)
catnet_finish(const float* __restrict__ bf, float* __restrict__ out)
{
    const int i = blockIdx.x * 256 + threadIdx.x;   // 1024 = 256 n x 4 o
    if (i < 1024) {
        const int n = i >> 2, o = i & 3;
        out[i] = g_part[n * 16 + o]     + g_part[n * 16 + 4 + o]
               + g_part[n * 16 + 8 + o] + g_part[n * 16 + 12 + o] + bf[o];
    }
}

extern "C" void kernel_launch(void* const* d_in, const int* in_sizes, int n_in,
                              void* d_out, int out_size, void* d_ws, size_t ws_size,
                              hipStream_t stream) {
    const float* x  = (const float*)d_in[0];
    const float* w1 = (const float*)d_in[1];
    const float* b1 = (const float*)d_in[2];
    const float* w2 = (const float*)d_in[3];
    const float* b2 = (const float*)d_in[4];
    const float* w3 = (const float*)d_in[5];
    const float* b3 = (const float*)d_in[6];
    const float* wf = (const float*)d_in[7];
    const float* bf = (const float*)d_in[8];
    float* outp = (float*)d_out;

    catnet_split<<<dim3(1024), dim3(512), 0, stream>>>(
        x, w1, b1, w2, b2, w3, b3, wf);
    catnet_finish<<<dim3(4), dim3(256), 0, stream>>>(bf, outp);
}

// Round 6
// 99.154 us; speedup vs baseline: 1.7800x; 1.7800x over previous
//
#include <hip/hip_runtime.h>

// CatNet_76553497084407 — SLAYER-style spiking CNN, fully collapsed over time.
//
// R13: cut DS instruction count ~4x. Six rounds of evidence: time responds
// ONLY to instruction count on memory pipes (R9 +DS->+16%, R12 +VMEM->+170%),
// never to stalls/conflicts/TLP (R8, R11 = 0). Pipe accounting for R8: VALU
// ~21k cyc/SIMD, DS ~39k cyc/CU (phase2 160 + phase4 224 ds_read_b32/thread,
// 5.8 cyc each) -> the shared LDS unit is the biggest term.
//   * Interstage buffers transposed to ci-quad-innermost float4:
//     r1q[ciq][i][4], r3q[ciq][p][4]. One ds_read_b128 = one window tap for
//     4 input channels. Lanes at 16B stride = bank-balanced (8 dwords/bank
//     per wave-inst), aligned by construction. Phase2: 160 b32 -> 40 b128;
//     phase4: 224 -> 56; phase2 output write 4 b32 -> 1 b128.
//   * Weights stay wave-uniform s_load (R9: LDS-staging cost +16%; R12:
//     per-lane weight addrs -> vector loads, +170%).
//   * Single dispatch again (grid 256 x 1024, bounds(1024,4) for VGPR
//     headroom: phase-2 windows hold 40 floats live).
//   * Keep: even/odd tap split, exact c/50 LDS rate table, 2e-4 risky
//     threshold, no-ballot pooled rate, float2 phase 0/5.
// Spill tripwire: WRITE_SIZE must stay ~tens of KB (spills were 190MB+).

#define T_STEPS 50
#define THETA   0.9999f

// component of a float4 by compile-time index (folds after unroll)
#define F4C(v, c) ((c) == 0 ? (v).x : (c) == 1 ? (v).y : (c) == 2 ? (v).z : (v).w)

// Exact-rounding rate: tbl[c] == c/50.0f computed with a true divide once.
__device__ __forceinline__ float spike_rate(float a, const float* __restrict__ tbl) {
    constexpr float INV = 50.0f / 0.9999f;
    float t = a * INV;
    float c = fminf(fmaxf(floorf(t), 0.0f), 50.0f);
    // fall back to the exact 50-step f32 sim when t is near an integer
    bool risky = (t > 0.5f) && (fabsf(t - rintf(t)) < 2e-4f);
    if (__ballot(risky)) {
        float v = 0.f, cnt = 0.f;
#pragma unroll 1
        for (int k = 0; k < T_STEPS; ++k) {
            v += a;
            float s = (v >= THETA) ? 1.0f : 0.0f;
            v -= s * THETA;
            cnt += s;
        }
        c = cnt;
    }
    return tbl[(int)c];
}

// No-ballot variant: only legal when the input provably cannot sit within
// 2e-4 of an integer boundary in t-units (pooled path: 1.1*k/50, margin 1.1e-3).
__device__ __forceinline__ float spike_rate_nb(float a, const float* __restrict__ tbl) {
    constexpr float INV = 50.0f / 0.9999f;
    float t = a * INV;
    float c = fminf(fmaxf(floorf(t), 0.0f), 50.0f);
    return tbl[(int)c];
}

extern "C" __global__ void __launch_bounds__(1024, 4)
catnet_kernel(const float* __restrict__ x,
              const float* __restrict__ w1, const float* __restrict__ b1,
              const float* __restrict__ w2, const float* __restrict__ b2,
              const float* __restrict__ w3, const float* __restrict__ b3,
              const float* __restrict__ wf, const float* __restrict__ bf,
              float* __restrict__ out)
{
    const int n    = blockIdx.x;
    const int tid  = threadIdx.x;
    const int wave = tid >> 6;
    const int lane = tid & 63;

    __shared__ float  xbar[182];        // [h+1], h in [0,180)
    __shared__ float4 r1qe[4][92];      // [ciq][i] = conv1 rate at even padded H=2i, ci quad
    __shared__ float4 r1qo[4][92];      // [ciq][i] = odd padded H=2i+1
    __shared__ float4 r3q[8][89];       // [ciq][p+1] = pooled rate, ci quad
    __shared__ alignas(16) float r4s[32][83];
    __shared__ float  ratetbl[51];      // exact c/50.0f
    __shared__ float  part[16];

    // zero conv pads + build exact-rate table
    const float4 z4 = make_float4(0.f, 0.f, 0.f, 0.f);
    if (tid < 4)               r1qe[tid][0]       = z4;   // H=0 pad
    if (tid >= 4  && tid < 8)  r1qo[tid - 4][90]  = z4;   // H=181 pad
    if (tid >= 8  && tid < 16) r3q[tid - 8][0]    = z4;   // p_idx=0 pad
    if (tid >= 16 && tid < 24) r3q[tid - 16][88]  = z4;   // p_idx=88 pad
    if (tid == 64)             { xbar[0] = 0.f; xbar[181] = 0.f; }
    if (tid >= 128 && tid < 179) ratetbl[tid - 128] = (float)(tid - 128) / 50.0f;

    // ---- phase 0: time-sum of input, 4 lanes per h, float2 loads ----
    const float* xn = x + (size_t)n * (180 * 50);
    if (tid < 720) {
        const int h = tid >> 2, q = tid & 3;
        const float2* row2 = reinterpret_cast<const float2*>(xn + h * 50);
        float s = 0.f;
        for (int k = q; k < 24; k += 4) { float2 v = row2[k]; s += v.x + v.y; }
        if (q == 0)                     { float2 v = row2[24]; s += v.x + v.y; }
        s += __shfl_xor(s, 1, 4);
        s += __shfl_xor(s, 2, 4);
        if (q == 0) xbar[h + 1] = s;
    }
    __syncthreads();

    // ---- phase 1: conv1 (1->16, k=3, pad=1), /T, +b1, rate ----
    for (int idx = tid; idx < 16 * 180; idx += 1024) {
        int c = idx / 180, h = idx - c * 180;
        float a = w1[c*3+0] * xbar[h] + w1[c*3+1] * xbar[h+1] + w1[c*3+2] * xbar[h+2];
        a = a / 50.0f + b1[c];
        float r = spike_rate(a, ratetbl);
        int H = h + 1;
        float* dst = (H & 1) ? (float*)&r1qo[c >> 2][H >> 1]
                             : (float*)&r1qe[c >> 2][H >> 1];
        dst[c & 3] = r;
    }
    __syncthreads();

    // ---- phase 2: conv2 (16->32, k=9, pad=1) + rate + pool(2)*1.1 + rate ----
    // 8 groups of 128 threads: g = tid>>7 (wave-uniform), p = tid&127 < 87.
    // Thread computes conv2 at h=2p,2p+1 (shared 10-tap window) for 4 out-ch.
    // Per ci-quad: 10 ds_read_b128 = window taps for 4 input channels.
    // Tap d (padded H=2p+d): d even -> F4C(we[d/2]), d odd -> F4C(wo[(d-1)/2]).
    {
        const int g   = __builtin_amdgcn_readfirstlane(tid >> 7);   // 0..7
        const int p   = tid & 127;
        const bool act = p < 87;
        const int pr  = act ? p : 0;
        const float* wb = w2 + g * 4 * 144;   // [oc][ci][kh], oc stride 144

        float a0[4], a1[4];
#pragma unroll
        for (int j = 0; j < 4; ++j) { a0[j] = b2[g*4 + j]; a1[j] = a0[j]; }

#pragma unroll 1
        for (int qd = 0; qd < 4; ++qd) {
            float4 we[5], wo[5];
#pragma unroll
            for (int d = 0; d < 5; ++d) { we[d] = r1qe[qd][pr + d]; wo[d] = r1qo[qd][pr + d]; }

#pragma unroll
            for (int c4 = 0; c4 < 4; ++c4) {
                const int ci = qd * 4 + c4;
#pragma unroll
                for (int j = 0; j < 4; ++j) {
                    const float* wj = wb + j * 144 + ci * 9;
#pragma unroll
                    for (int kh = 0; kh < 9; ++kh) {
                        float wv  = wj[kh];
                        float xlo = (kh & 1) ? F4C(wo[kh >> 1], c4)
                                             : F4C(we[kh >> 1], c4);        // tap kh
                        float xhi = (kh & 1) ? F4C(we[(kh + 1) >> 1], c4)
                                             : F4C(wo[kh >> 1], c4);        // tap kh+1
                        a0[j] += wv * xlo;     // h = 2p
                        a1[j] += wv * xhi;     // h = 2p+1
                    }
                }
            }
        }
        float r3t[4];
#pragma unroll
        for (int j = 0; j < 4; ++j) {
            float r20 = spike_rate(a0[j], ratetbl);
            float r21 = spike_rate(a1[j], ratetbl);
            r3t[j] = spike_rate_nb(1.1f * (r20 + r21), ratetbl);
        }
        if (act) r3q[g][p + 1] = make_float4(r3t[0], r3t[1], r3t[2], r3t[3]);
    }
    __syncthreads();

    // ---- phase 4: conv3 (32->32, k=7, pad=1) + rate ----
    // 16 waves = 8 out-ch-groups(4) x 2 h-halves; lanes -> h.
    // Per ci-quad: 7 ds_read_b128 window taps (4 input channels each).
    {
        const int gg   = __builtin_amdgcn_readfirstlane(wave >> 1);  // 0..7
        const int g4   = gg * 4;
        const int half = wave & 1;
        const int cnt  = half ? 41 : 42;
        const bool act = lane < cnt;
        const int h0   = half * 42 + lane;    // valid max 82; window max 88
        const int hr   = act ? h0 : 0;
        const float* wb = w3 + g4 * 224;      // [oc][ci][kh], oc stride 224

        float a[4];
#pragma unroll
        for (int j = 0; j < 4; ++j) a[j] = b3[g4 + j];

#pragma unroll 1
        for (int q = 0; q < 8; ++q) {
            float4 rv[7];
#pragma unroll
            for (int d = 0; d < 7; ++d) rv[d] = r3q[q][hr + d];

#pragma unroll
            for (int c4 = 0; c4 < 4; ++c4) {
                const int ci = q * 4 + c4;
#pragma unroll
                for (int j = 0; j < 4; ++j) {
                    const float* wj = wb + j * 224 + ci * 7;
#pragma unroll
                    for (int kh = 0; kh < 7; ++kh)
                        a[j] += wj[kh] * F4C(rv[kh], c4);
                }
            }
        }
#pragma unroll
        for (int j = 0; j < 4; ++j) {
            float r = spike_rate(a[j], ratetbl);
            if (act) r4s[g4 + j][h0] = r;
        }
    }
    __syncthreads();

    // ---- phase 5: dense [32*83] -> 4 outputs; 4 waves per output, float2 ----
    {
        const int o = wave >> 2, q = wave & 3;
        const float2* r42 = reinterpret_cast<const float2*>(&r4s[0][0]);
        const float2* wo2 = reinterpret_cast<const float2*>(wf + o * (32 * 83));
        float acc = 0.f;
        for (int j = q * 64 + lane; j < 1328; j += 256) {
            float2 rv = r42[j], wv = wo2[j];
            acc += rv.x * wv.x + rv.y * wv.y;
        }
#pragma unroll
        for (int off = 32; off > 0; off >>= 1)
            acc += __shfl_down(acc, off, 64);
        if (lane == 0) part[wave] = acc;
    }
    __syncthreads();
    if (tid < 4) {
        float s = part[tid*4] + part[tid*4+1] + part[tid*4+2] + part[tid*4+3];
        out[n * 4 + tid] = s + bf[tid];
    }
}

extern "C" void kernel_launch(void* const* d_in, const int* in_sizes, int n_in,
                              void* d_out, int out_size, void* d_ws, size_t ws_size,
                              hipStream_t stream) {
    const float* x  = (const float*)d_in[0];
    const float* w1 = (const float*)d_in[1];
    const float* b1 = (const float*)d_in[2];
    const float* w2 = (const float*)d_in[3];
    const float* b2 = (const float*)d_in[4];
    const float* w3 = (const float*)d_in[5];
    const float* b3 = (const float*)d_in[6];
    const float* wf = (const float*)d_in[7];
    const float* bf = (const float*)d_in[8];
    float* outp = (float*)d_out;

    catnet_kernel<<<dim3(256), dim3(1024), 0, stream>>>(
        x, w1, b1, w2, b2, w3, b3, wf, bf, outp);
}